// Round 10
// baseline (1254.969 us; speedup 1.0000x reference)
//
#include <hip/hip_runtime.h>
#include <math.h>

#define PI_D 3.14159265358979323846

typedef float f16v __attribute__((ext_vector_type(16)));

// ---------------- tables ----------------
// tz2[z][k][2]: c2r twiddles {2c/S, -2s/S}; tzk[k][z][2]: forward z twiddles {c,s}
__global__ void k_tables(float* tzf, float* tzi, float* tz2, float* tzk,
                         float* txf, float* txi) {
    int t = blockIdx.x * blockDim.x + threadIdx.x;
    if (t < 320) {
        int z = t >> 3, k = t & 7;
        double ang = -2.0 * PI_D * (double)(z * k) / 40.0;
        tzf[t * 2] = (float)cos(ang); tzf[t * 2 + 1] = (float)sin(ang);
        tzi[t * 2] = (float)cos(-ang); tzi[t * 2 + 1] = (float)sin(-ang);
        double s = 1.0 / 163840.0;
        double f = (k == 0) ? s : 2.0 * s;
        tz2[t * 2] = (float)(f * cos(-ang));
        tz2[t * 2 + 1] = (k == 0) ? 0.0f : (float)(-f * sin(-ang));
        tzk[(k * 40 + z) * 2] = (float)cos(ang);
        tzk[(k * 40 + z) * 2 + 1] = (float)sin(ang);
    }
    if (t < 1472) {
        int xx = t / 23, m = t % 23;
        double ang = -2.0 * PI_D * (double)(xx * (m - 11)) / 64.0;
        txf[t * 2] = (float)cos(ang); txf[t * 2 + 1] = (float)sin(ang);
        txi[t * 2] = (float)cos(-ang); txi[t * 2 + 1] = (float)sin(-ang);
    }
}

// transposes: w2t[l][j][o]=w2[l][o][j]; wwt[l][i][o]=ww[l][o][i]; w1t[l][i][j]=w1[l][j][i]
// q1t[i][j] = qw1[j][i]  (64 x 256)
__global__ void k_wtrans(const float* __restrict__ w2, const float* __restrict__ ww,
                         const float* __restrict__ w1, const float* __restrict__ qw1,
                         float* __restrict__ w2t, float* __restrict__ wwt,
                         float* __restrict__ w1t, float* __restrict__ q1t) {
    int gid = blockIdx.x * blockDim.x + threadIdx.x;
    if (gid < 16384) {
        int l = gid >> 12, r = gid & 4095, o = r >> 6, i = r & 63;
        w2t[l * 4096 + i * 64 + o] = w2[l * 4096 + o * 64 + i];
        wwt[l * 4096 + i * 64 + o] = ww[l * 4096 + o * 64 + i];
        w1t[l * 4096 + i * 64 + o] = w1[l * 4096 + o * 64 + i];
        int j = gid >> 6, iq = gid & 63;
        q1t[iq * 256 + j] = qw1[gid];
    }
}

// ---------------- lift ----------------
__global__ void k_lift(const float* __restrict__ xin, const float* __restrict__ pw,
                       const float* __restrict__ pb, float* __restrict__ xo) {
    int gid = blockIdx.x * 256 + threadIdx.x;   // 327680 total
    int b = gid / 163840, p = gid % 163840;
    int y = p / 2560, xx = (p / 40) % 64, z = p % 40;
    float v[13];
#pragma unroll
    for (int i = 0; i < 10; i++) v[i] = xin[(size_t)gid * 10 + i];
    v[10] = (float)((double)y / 63.0);
    v[11] = (float)((double)xx / 63.0);
    v[12] = (float)((double)z / 39.0);
    size_t ob = (size_t)b * 10485760 + p;
    for (int c = 0; c < 64; c++) {
        float a = pb[c];
#pragma unroll
        for (int i = 0; i < 13; i++) a += pw[c * 13 + i] * v[i];
        xo[ob + (size_t)c * 163840] = a;
    }
}

// ---------------- forward z-DFT + x-DFT, b128/b64 LDS reads ----------------
// grid (b,c,y)=8192, 256 threads. phase1: thread owns (xx, xx+32) sharing one
// twiddle stream: 6 LDS insts / 16 FMA per 4-z chunk. phase2: all-b64.
__global__ __launch_bounds__(256) void k_fwd_zx(const float* __restrict__ x,
        const float* __restrict__ tzk, const float* __restrict__ txf,
        float* __restrict__ Fx) {
    int bid = blockIdx.x;
    int b = bid >> 12, c = (bid >> 6) & 63, y = bid & 63;
    int t = threadIdx.x;
    __shared__ __align__(16) float xr_[2560];
    __shared__ __align__(16) float tzs[672];   // [k][42 f2] rows padded to 84 floats
    __shared__ __align__(16) float txs[2944];  // [xx][m][2]
    __shared__ __align__(16) float f1[1024];   // [xx][k][2]
    const float4* xrow4 = (const float4*)(x + ((size_t)((b * 64 + c) * 4096 + y * 64)) * 40);
    for (int idx = t; idx < 640; idx += 256) ((float4*)xr_)[idx] = xrow4[idx];
    for (int idx = t; idx < 160; idx += 256) {
        int k = idx / 20, q = idx % 20;
        ((float4*)tzs)[k * 21 + q] = ((const float4*)tzk)[idx];
    }
    for (int idx = t; idx < 736; idx += 256) ((float4*)txs)[idx] = ((const float4*)txf)[idx];
    __syncthreads();
    {
        int xx = t >> 3, k = t & 7;
        float sr0 = 0.f, si0 = 0.f, sr1 = 0.f, si1 = 0.f;
        const float2* tzp = (const float2*)(tzs + k * 84);
        const float4* X0 = (const float4*)(xr_ + xx * 40);
        const float4* X1 = (const float4*)(xr_ + (xx + 32) * 40);
        for (int zc = 0; zc < 10; zc++) {
            float4 A = X0[zc], B = X1[zc];
            float2 T0 = tzp[zc * 4], T1v = tzp[zc * 4 + 1];
            float2 T2v = tzp[zc * 4 + 2], T3v = tzp[zc * 4 + 3];
            sr0 = fmaf(A.x, T0.x, sr0);  si0 = fmaf(A.x, T0.y, si0);
            sr0 = fmaf(A.y, T1v.x, sr0); si0 = fmaf(A.y, T1v.y, si0);
            sr0 = fmaf(A.z, T2v.x, sr0); si0 = fmaf(A.z, T2v.y, si0);
            sr0 = fmaf(A.w, T3v.x, sr0); si0 = fmaf(A.w, T3v.y, si0);
            sr1 = fmaf(B.x, T0.x, sr1);  si1 = fmaf(B.x, T0.y, si1);
            sr1 = fmaf(B.y, T1v.x, sr1); si1 = fmaf(B.y, T1v.y, si1);
            sr1 = fmaf(B.z, T2v.x, sr1); si1 = fmaf(B.z, T2v.y, si1);
            sr1 = fmaf(B.w, T3v.x, sr1); si1 = fmaf(B.w, T3v.y, si1);
        }
        ((float2*)f1)[xx * 8 + k] = make_float2(sr0, si0);
        ((float2*)f1)[(xx + 32) * 8 + k] = make_float2(sr1, si1);
    }
    __syncthreads();
    if (t < 184) {
        int m = t >> 3, k = t & 7;
        float sr = 0.f, si = 0.f;
        const float2* f1p = (const float2*)f1;
        const float2* txp = (const float2*)txs;
        for (int xx = 0; xx < 64; xx++) {
            float2 a = f1p[xx * 8 + k];
            float2 w = txp[xx * 23 + m];
            sr = fmaf(a.x, w.x, sr); sr = fmaf(-a.y, w.y, sr);
            si = fmaf(a.x, w.y, si); si = fmaf(a.y, w.x, si);
        }
        size_t g = ((size_t)(((b * 64 + c) * 64 + y) * 23 + m) * 8 + k) * 2;
        Fx[g] = sr; Fx[g + 1] = si;
    }
}

// ---------------- forward y-DFT: thread=(n,kpair), b128 s + b64 table --------
__global__ __launch_bounds__(128) void k_fwd_y(const float* __restrict__ Fx,
        const float* __restrict__ txf, float* __restrict__ Xs) {
    int bid = blockIdx.x;
    int b = bid / 1472, rem = bid % 1472, c = rem / 23, m = rem % 23;
    int t = threadIdx.x;
    __shared__ __align__(16) float s[1024];    // [y][k][2]
    __shared__ __align__(16) float txs[2944];
    for (int idx = t; idx < 512; idx += 128) {
        int y = idx >> 3, k = idx & 7;
        size_t g = ((size_t)(((b * 64 + c) * 64 + y) * 23 + m) * 8 + k);
        ((float2*)s)[idx] = ((const float2*)Fx)[g];
    }
    for (int idx = t; idx < 736; idx += 128) ((float4*)txs)[idx] = ((const float4*)txf)[idx];
    __syncthreads();
    if (t < 92) {
        int n = t >> 2, kp = t & 3;
        float sr0 = 0.f, si0 = 0.f, sr1 = 0.f, si1 = 0.f;
        const float2* txp = (const float2*)txs;
        for (int y = 0; y < 64; y++) {
            float4 S = *(const float4*)&s[y * 16 + kp * 4];
            float2 w = txp[y * 23 + n];
            sr0 = fmaf(S.x, w.x, sr0); sr0 = fmaf(-S.y, w.y, sr0);
            si0 = fmaf(S.x, w.y, si0); si0 = fmaf(S.y, w.x, si0);
            sr1 = fmaf(S.z, w.x, sr1); sr1 = fmaf(-S.w, w.y, sr1);
            si1 = fmaf(S.z, w.y, si1); si1 = fmaf(S.w, w.x, si1);
        }
        size_t g = ((size_t)(((b * 64 + c) * 23 + n) * 23 + m)) * 16 + kp * 4;
        *(float4*)&Xs[g] = make_float4(sr0, si0, sr1, si1);
    }
}

// ---------------- mode mixing (unchanged) ----------------
__global__ void k_mix(const float* __restrict__ Xs, const float* __restrict__ WLC,
                      const float* __restrict__ WLR, float* __restrict__ Md) {
    int bid = blockIdx.x;
    int n = bid / 23, m = bid % 23;
    int a = n, c = m, yy, w;
    if (c >= 11) { yy = a; w = c - 11; } else { yy = 22 - a; w = 11 - c; }
    int isLC, idx;
    if (yy >= 12) {
        int p = yy - 12, q = w;
        if (q == 0) { isLC = 1; idx = p + 1; } else { isLC = 0; idx = p * 11 + (q - 1); }
    } else {
        if (w == 0) { isLC = 1; idx = 11 - yy; }
        else {
            int p = w - 1, q = 11 - yy;
            if (q == 0) { isLC = 1; idx = p + 1; } else { isLC = 0; idx = p * 11 + (q - 1); }
        }
    }
    const float* src = isLC ? WLC : WLR;
    int stride = isLC ? 96 : 968;
    int base8 = idx * 8;

    int t = threadIdx.x;
    int o = t >> 3, tt = t & 7;
    __shared__ __align__(16) float wl[8 * 64 * 8];
    __shared__ float xl[256];
    float aR0 = 0.f, aI0 = 0.f, aR1 = 0.f, aI1 = 0.f;
    for (int i0 = 0; i0 < 64; i0 += 8) {
        {
            int il = t >> 6, oo = t & 63;
            const float4* g = (const float4*)(src + (size_t)((i0 + il) * 64 + oo) * stride + base8);
            float4 A = g[0], B = g[1];
            float4* d = (float4*)&wl[(il * 64 + oo) * 8];
            d[0] = A; d[1] = B;
        }
        if (t < 256) {
            int bb = t >> 7, il = (t >> 4) & 7, kk = (t >> 1) & 7, ri = t & 1;
            xl[t] = Xs[((size_t)(((bb * 64 + i0 + il) * 23 + n) * 23 + m) * 8 + kk) * 2 + ri];
        }
        __syncthreads();
#pragma unroll
        for (int il = 0; il < 8; il++) {
            float wv = wl[(il * 64 + o) * 8 + tt];
            float xr0 = xl[(il * 8 + tt) * 2], xi0 = xl[(il * 8 + tt) * 2 + 1];
            float xr1 = xl[128 + (il * 8 + tt) * 2], xi1 = xl[128 + (il * 8 + tt) * 2 + 1];
            aR0 += wv * xr0; aI0 += wv * xi0;
            aR1 += wv * xr1; aI1 += wv * xi1;
        }
        __syncthreads();
    }
    size_t ob0 = ((size_t)((o * 23 + n) * 23 + m) * 8 + tt) * 2;
    size_t ob1 = ((size_t)(((64 + o) * 23 + n) * 23 + m) * 8 + tt) * 2;
    Md[ob0] = aR0; Md[ob0 + 1] = aI0;
    Md[ob1] = aR1; Md[ob1 + 1] = aI1;
}

// ---------------- inverse y: thread=(y,kpair) ----------------
__global__ __launch_bounds__(256) void k_inv_y(const float* __restrict__ Md,
        const float* __restrict__ txi, float* __restrict__ T1) {
    int bid = blockIdx.x;
    int b = bid / 1472, rem = bid % 1472, o = rem / 23, m = rem % 23;
    int t = threadIdx.x;
    __shared__ __align__(16) float s[368];     // [n][k][2]
    __shared__ __align__(16) float txs[2944];
    if (t < 184) {
        int n = t >> 3, kk = t & 7;
        size_t g = ((size_t)(((b * 64 + o) * 23 + n) * 23 + m) * 8 + kk);
        ((float2*)s)[t] = ((const float2*)Md)[g];
    }
    for (int idx = t; idx < 736; idx += 256) ((float4*)txs)[idx] = ((const float4*)txi)[idx];
    __syncthreads();
    int y = t >> 2, kp = t & 3;
    float sr0 = 0.f, si0 = 0.f, sr1 = 0.f, si1 = 0.f;
    const float2* txp = (const float2*)txs;
    for (int n = 0; n < 23; n++) {
        float4 S = *(const float4*)&s[n * 16 + kp * 4];
        float2 w = txp[y * 23 + n];
        sr0 = fmaf(S.x, w.x, sr0); sr0 = fmaf(-S.y, w.y, sr0);
        si0 = fmaf(S.x, w.y, si0); si0 = fmaf(S.y, w.x, si0);
        sr1 = fmaf(S.z, w.x, sr1); sr1 = fmaf(-S.w, w.y, sr1);
        si1 = fmaf(S.z, w.y, si1); si1 = fmaf(S.w, w.x, si1);
    }
    size_t g = ((size_t)(((b * 64 + o) * 64 + y) * 23 + m)) * 16 + kp * 4;
    *(float4*)&T1[g] = make_float4(sr0, si0, sr1, si1);
}

// ---------------- inverse x: thread=(xx,kpair) ----------------
__global__ __launch_bounds__(256) void k_inv_x(const float* __restrict__ T1,
        const float* __restrict__ txi, float* __restrict__ T2) {
    int bid = blockIdx.x;
    int b = bid >> 12, o = (bid >> 6) & 63, y = bid & 63;
    int t = threadIdx.x;
    __shared__ __align__(16) float s[368];     // [m][k][2]
    __shared__ __align__(16) float txs[2944];
    {
        const float4* src = (const float4*)(T1 + (size_t)((b * 64 + o) * 64 + y) * 368);
        if (t < 92) ((float4*)s)[t] = src[t];
    }
    for (int idx = t; idx < 736; idx += 256) ((float4*)txs)[idx] = ((const float4*)txi)[idx];
    __syncthreads();
    int xx = t >> 2, kp = t & 3;
    float sr0 = 0.f, si0 = 0.f, sr1 = 0.f, si1 = 0.f;
    const float2* txp = (const float2*)txs;
    for (int m = 0; m < 23; m++) {
        float4 S = *(const float4*)&s[m * 16 + kp * 4];
        float2 w = txp[xx * 23 + m];
        sr0 = fmaf(S.x, w.x, sr0); sr0 = fmaf(-S.y, w.y, sr0);
        si0 = fmaf(S.x, w.y, si0); si0 = fmaf(S.y, w.x, si0);
        sr1 = fmaf(S.z, w.x, sr1); sr1 = fmaf(-S.w, w.y, sr1);
        si1 = fmaf(S.z, w.y, si1); si1 = fmaf(S.w, w.x, si1);
    }
    size_t g = ((size_t)((b * 64 + o) * 4096 + y * 64 + xx)) * 16 + kp * 4;
    *(float4*)&T2[g] = make_float4(sr0, si0, sr1, si1);
}

// ---------------- inline erf-based GELU (A&S 7.1.26, |err|<=1.5e-7) ----
__device__ __forceinline__ float gelu_fast(float x) {
    float u = x * 0.70710678118654752f;
    float a = fabsf(u);
    float t = 1.0f / (1.0f + 0.3275911f * a);
    float poly = t * (0.254829592f + t * (-0.284496736f + t * (1.421413741f +
                 t * (-1.453152027f + t * 1.061405429f))));
    float erfa = 1.0f - poly * __expf(-a * a);
    float er = copysignf(erfa, u);
    return 0.5f * x * (1.0f + er);
}

// ---------------- mlp1: k-space GEMM + c2r + gelu (unchanged from R8) -------
__global__ __launch_bounds__(256) void k_mlp1(
    const float* __restrict__ t2buf, const float* __restrict__ w1t,
    const float* __restrict__ b1, const float* __restrict__ tz2g,
    float* __restrict__ g) {
    __shared__ __align__(16) float T2s[4096];   // [4 sites][64 i][16]
    __shared__ __align__(16) float w1ls[4096];  // [64 i][64 j]
    __shared__ __align__(16) float Hs[4096];    // [4 sites][64 j][16]
    __shared__ float tzls[640];
    int t = threadIdx.x;
    int site0 = blockIdx.x * 4;
    for (int idx = t; idx < 1024; idx += 256) {
        int sl = idx >> 8, r = idx & 255, i = r >> 2, q = r & 3;
        int site = site0 + sl;
        int b = site >> 12, yx = site & 4095;
        const float4* src = (const float4*)(t2buf + ((size_t)(b * 64 + i) * 4096 + yx) * 16 + q * 4);
        *(float4*)&T2s[sl * 1024 + i * 16 + q * 4] = *src;
    }
    for (int idx = t; idx < 1024; idx += 256)
        *(float4*)&w1ls[idx * 4] = ((const float4*)w1t)[idx];
    for (int idx = t; idx < 640; idx += 256) tzls[idx] = tz2g[idx];
    __syncthreads();
    {
        int sl = t >> 6, u = t & 63;
        int j0 = (u >> 2) * 4, kr0 = (u & 3) * 4;
        float c0 = 0.f, c1 = 0.f, c2 = 0.f, c3 = 0.f, c4 = 0.f, c5 = 0.f, c6 = 0.f, c7 = 0.f;
        float c8 = 0.f, c9 = 0.f, c10 = 0.f, c11 = 0.f, c12 = 0.f, c13 = 0.f, c14 = 0.f, c15 = 0.f;
        int tb = sl * 1024 + kr0;
        for (int i = 0; i < 64; i++) {
            float4 W = *(const float4*)&w1ls[i * 64 + j0];
            float4 T = *(const float4*)&T2s[tb + i * 16];
            c0  = fmaf(W.x, T.x, c0);  c1  = fmaf(W.x, T.y, c1);
            c2  = fmaf(W.x, T.z, c2);  c3  = fmaf(W.x, T.w, c3);
            c4  = fmaf(W.y, T.x, c4);  c5  = fmaf(W.y, T.y, c5);
            c6  = fmaf(W.y, T.z, c6);  c7  = fmaf(W.y, T.w, c7);
            c8  = fmaf(W.z, T.x, c8);  c9  = fmaf(W.z, T.y, c9);
            c10 = fmaf(W.z, T.z, c10); c11 = fmaf(W.z, T.w, c11);
            c12 = fmaf(W.w, T.x, c12); c13 = fmaf(W.w, T.y, c13);
            c14 = fmaf(W.w, T.z, c14); c15 = fmaf(W.w, T.w, c15);
        }
        int hb = sl * 1024 + j0 * 16 + kr0;
        *(float4*)&Hs[hb]      = make_float4(c0, c1, c2, c3);
        *(float4*)&Hs[hb + 16] = make_float4(c4, c5, c6, c7);
        *(float4*)&Hs[hb + 32] = make_float4(c8, c9, c10, c11);
        *(float4*)&Hs[hb + 48] = make_float4(c12, c13, c14, c15);
    }
    __syncthreads();
    {
        int sl = t >> 6, j = t & 63;
        int site = site0 + sl;
        int b = site >> 12, yx = site & 4095;
        int hb = sl * 1024 + j * 16;
        float4 H0 = *(const float4*)&Hs[hb];
        float4 H1 = *(const float4*)&Hs[hb + 4];
        float4 H2 = *(const float4*)&Hs[hb + 8];
        float4 H3 = *(const float4*)&Hs[hb + 12];
        float b1j = b1[j];
        size_t obase = (size_t)j * 327680 + (size_t)b * 163840 + yx * 40;
        for (int zc = 0; zc < 10; zc++) {
            float4 outv;
#pragma unroll
            for (int zi = 0; zi < 4; zi++) {
                int z = zc * 4 + zi;
                const float4* tz = (const float4*)&tzls[z * 16];
                float4 T0 = tz[0], T1v = tz[1], T2v = tz[2], T3 = tz[3];
                float v = H0.x * T0.x;
                v = fmaf(H0.y, T0.y, v); v = fmaf(H0.z, T0.z, v); v = fmaf(H0.w, T0.w, v);
                v = fmaf(H1.x, T1v.x, v); v = fmaf(H1.y, T1v.y, v);
                v = fmaf(H1.z, T1v.z, v); v = fmaf(H1.w, T1v.w, v);
                v = fmaf(H2.x, T2v.x, v); v = fmaf(H2.y, T2v.y, v);
                v = fmaf(H2.z, T2v.z, v); v = fmaf(H2.w, T2v.w, v);
                v = fmaf(H3.x, T3.x, v); v = fmaf(H3.y, T3.y, v);
                v = fmaf(H3.z, T3.z, v); v = fmaf(H3.w, T3.w, v);
                float h = b1j + v;
                float gv = gelu_fast(h);
                if (zi == 0) outv.x = gv; else if (zi == 1) outv.y = gv;
                else if (zi == 2) outv.z = gv; else outv.w = gv;
            }
            *(float4*)&g[obase + zc * 4] = outv;
        }
    }
}

// ---------------- mlp2 v3: 8o x 8p register tile, x/g from GLOBAL -----------
// LDS delivers only weights (2 b128 per 64 FMA-inst). 256 points/block, in-place
// safe: block touches only its own point range; x reads precede stores.
#define FMAR8(R, Wc) \
    a##R##0 = fmaf(Wc, X0.x, a##R##0); a##R##1 = fmaf(Wc, X0.y, a##R##1); \
    a##R##2 = fmaf(Wc, X0.z, a##R##2); a##R##3 = fmaf(Wc, X0.w, a##R##3); \
    a##R##4 = fmaf(Wc, X1.x, a##R##4); a##R##5 = fmaf(Wc, X1.y, a##R##5); \
    a##R##6 = fmaf(Wc, X1.z, a##R##6); a##R##7 = fmaf(Wc, X1.w, a##R##7);

__global__ __launch_bounds__(256) void k_mlp2(
    const float* __restrict__ g, float* __restrict__ x,
    const float* __restrict__ w2t, const float* __restrict__ b2,
    const float* __restrict__ wwt, const float* __restrict__ wb, int dorelu) {
    __shared__ __align__(16) float wls[4096];  // [64][64]
    int t = threadIdx.x;
    int P0 = blockIdx.x * 256;
    int b = P0 / 163840, pl = P0 % 163840;
    size_t xbase = (size_t)b * 10485760 + pl;
    int o0 = (t >> 5) * 8, p0 = (t & 31) * 8;
#define INITR(R) float a##R##0 = b2[o0 + R] + wb[o0 + R]; \
    float a##R##1 = a##R##0, a##R##2 = a##R##0, a##R##3 = a##R##0, \
          a##R##4 = a##R##0, a##R##5 = a##R##0, a##R##6 = a##R##0, a##R##7 = a##R##0;
    INITR(0) INITR(1) INITR(2) INITR(3) INITR(4) INITR(5) INITR(6) INITR(7)
#undef INITR
    for (int idx = t; idx < 1024; idx += 256)
        ((float4*)wls)[idx] = ((const float4*)wwt)[idx];
    __syncthreads();
    for (int i = 0; i < 64; i++) {
        const float4* wp = (const float4*)&wls[i * 64 + o0];
        float4 W0 = wp[0], W1 = wp[1];
        const float* xp = x + xbase + (size_t)i * 163840 + p0;
        float4 X0 = *(const float4*)xp, X1 = *(const float4*)(xp + 4);
        FMAR8(0, W0.x) FMAR8(1, W0.y) FMAR8(2, W0.z) FMAR8(3, W0.w)
        FMAR8(4, W1.x) FMAR8(5, W1.y) FMAR8(6, W1.z) FMAR8(7, W1.w)
    }
    __syncthreads();
    for (int idx = t; idx < 1024; idx += 256)
        ((float4*)wls)[idx] = ((const float4*)w2t)[idx];
    __syncthreads();
    for (int j = 0; j < 64; j++) {
        const float4* wp = (const float4*)&wls[j * 64 + o0];
        float4 W0 = wp[0], W1 = wp[1];
        const float* gp = g + (size_t)j * 327680 + P0 + p0;
        float4 X0 = *(const float4*)gp, X1 = *(const float4*)(gp + 4);
        FMAR8(0, W0.x) FMAR8(1, W0.y) FMAR8(2, W0.z) FMAR8(3, W0.w)
        FMAR8(4, W1.x) FMAR8(5, W1.y) FMAR8(6, W1.z) FMAR8(7, W1.w)
    }
#define STROW(R) { \
        float4 R0, R1; \
        if (dorelu) { \
            R0 = make_float4(fmaxf(a##R##0, 0.f), fmaxf(a##R##1, 0.f), fmaxf(a##R##2, 0.f), fmaxf(a##R##3, 0.f)); \
            R1 = make_float4(fmaxf(a##R##4, 0.f), fmaxf(a##R##5, 0.f), fmaxf(a##R##6, 0.f), fmaxf(a##R##7, 0.f)); \
        } else { \
            R0 = make_float4(a##R##0, a##R##1, a##R##2, a##R##3); \
            R1 = make_float4(a##R##4, a##R##5, a##R##6, a##R##7); \
        } \
        float* op = x + xbase + (size_t)(o0 + R) * 163840 + p0; \
        *(float4*)op = R0; *(float4*)(op + 4) = R1; }
    STROW(0) STROW(1) STROW(2) STROW(3) STROW(4) STROW(5) STROW(6) STROW(7)
#undef STROW
}

// ---------------- final head v11: best-of-survey hybrid --------------------
// W-delivery survey (R3-R9): SMEM s_load 180us (best), per-lane LDS 205,
// LDS-broadcast 217, VMEM-broadcast 631. R6 vs R7 (2x SMEM traffic, 2x TLP)
// both ~180 -> plateau is latency/issue-structural, not byte/TLP-bound.
// v11 = R6's 2-pts/lane geometry (halves SMEM traffic, Xl 32KB -> 5 blk/CU)
// + R7's single s_load_dwordx16 per iter (1 lgkmcnt unit vs 4). Both parents
// measured 180+-4; hybrid strictly fewer insts + wait units than either.
__global__ __launch_bounds__(256) void k_head(
    const float* __restrict__ xcur, const float* __restrict__ q1t,
    const float* __restrict__ qb1, const float* __restrict__ qw2,
    const float* __restrict__ qb2, float* __restrict__ outp) {
    __shared__ __align__(16) float Xl[8192];   // [64 i][128 p]; reused as reduce buf
    int t = threadIdx.x;
    int P0 = blockIdx.x * 128;              // 163840 % 128 == 0: no b straddle
    int b = P0 / 163840, pl = P0 % 163840;
    size_t xbase = (size_t)b * 10485760 + pl;
    for (int idx = t; idx < 2048; idx += 256) {
        int i = idx >> 5, q = idx & 31;
        *(float4*)&Xl[i * 128 + q * 4] =
            *(const float4*)(xcur + xbase + (size_t)i * 163840 + q * 4);
    }
    __syncthreads();
    int w = t >> 6, lane = t & 63;
    int jb = __builtin_amdgcn_readfirstlane(w * 64);  // force SGPR j-base
    float outa0 = 0.f, outa1 = 0.f;
#define FMAJ(JJ, Wc) \
    accA##JJ = fmaf(Wc, x0, accA##JJ); accB##JJ = fmaf(Wc, x1, accB##JJ);
    for (int pass = 0; pass < 4; ++pass) {
        int j0 = jb + pass * 16;
        float accA0 = 0.f, accA1 = 0.f, accA2 = 0.f, accA3 = 0.f;
        float accA4 = 0.f, accA5 = 0.f, accA6 = 0.f, accA7 = 0.f;
        float accA8 = 0.f, accA9 = 0.f, accA10 = 0.f, accA11 = 0.f;
        float accA12 = 0.f, accA13 = 0.f, accA14 = 0.f, accA15 = 0.f;
        float accB0 = 0.f, accB1 = 0.f, accB2 = 0.f, accB3 = 0.f;
        float accB4 = 0.f, accB5 = 0.f, accB6 = 0.f, accB7 = 0.f;
        float accB8 = 0.f, accB9 = 0.f, accB10 = 0.f, accB11 = 0.f;
        float accB12 = 0.f, accB13 = 0.f, accB14 = 0.f, accB15 = 0.f;
#pragma unroll 2
        for (int i = 0; i < 64; ++i) {
            float x0 = Xl[i * 128 + lane];
            float x1 = Xl[i * 128 + 64 + lane];
            f16v W = *(const f16v*)(q1t + i * 256 + j0);  // uniform -> s_load_dwordx16
            FMAJ(0, W[0])   FMAJ(1, W[1])   FMAJ(2, W[2])   FMAJ(3, W[3])
            FMAJ(4, W[4])   FMAJ(5, W[5])   FMAJ(6, W[6])   FMAJ(7, W[7])
            FMAJ(8, W[8])   FMAJ(9, W[9])   FMAJ(10, W[10]) FMAJ(11, W[11])
            FMAJ(12, W[12]) FMAJ(13, W[13]) FMAJ(14, W[14]) FMAJ(15, W[15])
        }
#define EPIJ(JJ) { float bj = qb1[j0 + JJ]; float wj = qw2[j0 + JJ]; \
        outa0 = fmaf(wj, gelu_fast(accA##JJ + bj), outa0); \
        outa1 = fmaf(wj, gelu_fast(accB##JJ + bj), outa1); }
        EPIJ(0) EPIJ(1) EPIJ(2) EPIJ(3) EPIJ(4) EPIJ(5) EPIJ(6) EPIJ(7)
        EPIJ(8) EPIJ(9) EPIJ(10) EPIJ(11) EPIJ(12) EPIJ(13) EPIJ(14) EPIJ(15)
#undef EPIJ
    }
#undef FMAJ
    // cross-wave reduce overlaid on Xl (all passes done -> Xl reads finished)
    __syncthreads();
    Xl[w * 132 + lane] = outa0;
    Xl[w * 132 + 64 + lane] = outa1;
    __syncthreads();
    if (t < 128) {
        float s = qb2[0];
#pragma unroll
        for (int w2 = 0; w2 < 4; ++w2) s += Xl[w2 * 132 + t];
        outp[P0 + t] = s;
    }
}

extern "C" void kernel_launch(void* const* d_in, const int* in_sizes, int n_in,
                              void* d_out, int out_size, void* d_ws, size_t ws_size,
                              hipStream_t stream) {
    const float* x_in = (const float*)d_in[0];
    const float* p_w  = (const float*)d_in[1];
    const float* p_b  = (const float*)d_in[2];
    const float* W_LC = (const float*)d_in[3];
    const float* W_LR = (const float*)d_in[4];
    const float* m_w1 = (const float*)d_in[5];
    const float* m_b1 = (const float*)d_in[6];
    const float* m_w2 = (const float*)d_in[7];
    const float* m_b2 = (const float*)d_in[8];
    const float* w_w  = (const float*)d_in[9];
    const float* w_b  = (const float*)d_in[10];
    const float* q_w1 = (const float*)d_in[11];
    const float* q_b1 = (const float*)d_in[12];
    const float* q_w2 = (const float*)d_in[13];
    const float* q_b2 = (const float*)d_in[14];

    char* ws = (char*)d_ws;
    // table region [0, 65536)
    float* tzf = (float*)(ws + 0);        // 2560 B
    float* tzi = (float*)(ws + 2560);     // 2560 B
    float* tz2 = (float*)(ws + 5120);     // 2560 B
    float* tzk = (float*)(ws + 7680);     // 2560 B
    float* txf = (float*)(ws + 10240);    // 11776 B
    float* txi = (float*)(ws + 22016);    // 11776 B -> 33792
    float* w2t = (float*)(ws + 65536);
    float* wwt = (float*)(ws + 131072);
    float* w1t = (float*)(ws + 196608);
    float* q1t = (float*)(ws + 262144);   // 65536 B: qw1 transposed [64][256]
    size_t off = 327680;
    float* xA = (float*)(ws + off); off += 83886080ull;
    float* gbuf = (float*)(ws + off); off += 83886080ull;
    float* Fx = (float*)(ws + off); off += 12058624ull;
    float* Xs = (float*)(ws + off); off += 4333568ull;
    float* Md = (float*)(ws + off); off += 4333568ull;
    float* T1 = (float*)(ws + off); off += 12058624ull;
    float* T2 = (float*)(ws + off); off += 33554432ull;

    k_tables<<<6, 256, 0, stream>>>(tzf, tzi, tz2, tzk, txf, txi);
    k_wtrans<<<64, 256, 0, stream>>>(m_w2, w_w, m_w1, q_w1, w2t, wwt, w1t, q1t);
    k_lift<<<1280, 256, 0, stream>>>(x_in, p_w, p_b, xA);

    for (int l = 0; l < 4; l++) {
        k_fwd_zx<<<8192, 256, 0, stream>>>(xA, tzk, txf, Fx);
        k_fwd_y<<<2944, 128, 0, stream>>>(Fx, txf, Xs);
        k_mix<<<529, 512, 0, stream>>>(Xs, W_LC + (size_t)l * 393216,
                                       W_LR + (size_t)l * 3964928, Md);
        k_inv_y<<<2944, 256, 0, stream>>>(Md, txi, T1);
        k_inv_x<<<8192, 256, 0, stream>>>(T1, txi, T2);
        k_mlp1<<<2048, 256, 0, stream>>>(T2, w1t + (size_t)l * 4096, m_b1 + l * 64,
                                         tz2, gbuf);
        k_mlp2<<<1280, 256, 0, stream>>>(gbuf, xA, w2t + (size_t)l * 4096, m_b2 + l * 64,
                                         wwt + (size_t)l * 4096, w_b + l * 64,
                                         (l < 3) ? 1 : 0);
    }
    k_head<<<2560, 256, 0, stream>>>(xA, q1t, q_b1, q_w2, q_b2, (float*)d_out);
}

// Round 11
// 1243.245 us; speedup vs baseline: 1.0094x; 1.0094x over previous
//
#include <hip/hip_runtime.h>
#include <math.h>

#define PI_D 3.14159265358979323846

// ---------------- tables ----------------
// tz2[z][k][2]: c2r twiddles {2c/S, -2s/S}; tzk[k][z][2]: forward z twiddles {c,s}
__global__ void k_tables(float* tzf, float* tzi, float* tz2, float* tzk,
                         float* txf, float* txi) {
    int t = blockIdx.x * blockDim.x + threadIdx.x;
    if (t < 320) {
        int z = t >> 3, k = t & 7;
        double ang = -2.0 * PI_D * (double)(z * k) / 40.0;
        tzf[t * 2] = (float)cos(ang); tzf[t * 2 + 1] = (float)sin(ang);
        tzi[t * 2] = (float)cos(-ang); tzi[t * 2 + 1] = (float)sin(-ang);
        double s = 1.0 / 163840.0;
        double f = (k == 0) ? s : 2.0 * s;
        tz2[t * 2] = (float)(f * cos(-ang));
        tz2[t * 2 + 1] = (k == 0) ? 0.0f : (float)(-f * sin(-ang));
        tzk[(k * 40 + z) * 2] = (float)cos(ang);
        tzk[(k * 40 + z) * 2 + 1] = (float)sin(ang);
    }
    if (t < 1472) {
        int xx = t / 23, m = t % 23;
        double ang = -2.0 * PI_D * (double)(xx * (m - 11)) / 64.0;
        txf[t * 2] = (float)cos(ang); txf[t * 2 + 1] = (float)sin(ang);
        txi[t * 2] = (float)cos(-ang); txi[t * 2 + 1] = (float)sin(-ang);
    }
}

// transposes: w2t[l][j][o]=w2[l][o][j]; wwt[l][i][o]=ww[l][o][i]; w1t[l][i][j]=w1[l][j][i]
// q1t[i][j] = qw1[j][i]  (64 x 256)
__global__ void k_wtrans(const float* __restrict__ w2, const float* __restrict__ ww,
                         const float* __restrict__ w1, const float* __restrict__ qw1,
                         float* __restrict__ w2t, float* __restrict__ wwt,
                         float* __restrict__ w1t, float* __restrict__ q1t) {
    int gid = blockIdx.x * blockDim.x + threadIdx.x;
    if (gid < 16384) {
        int l = gid >> 12, r = gid & 4095, o = r >> 6, i = r & 63;
        w2t[l * 4096 + i * 64 + o] = w2[l * 4096 + o * 64 + i];
        wwt[l * 4096 + i * 64 + o] = ww[l * 4096 + o * 64 + i];
        w1t[l * 4096 + i * 64 + o] = w1[l * 4096 + o * 64 + i];
        int j = gid >> 6, iq = gid & 63;
        q1t[iq * 256 + j] = qw1[gid];
    }
}

// ---------------- lift ----------------
__global__ void k_lift(const float* __restrict__ xin, const float* __restrict__ pw,
                       const float* __restrict__ pb, float* __restrict__ xo) {
    int gid = blockIdx.x * 256 + threadIdx.x;   // 327680 total
    int b = gid / 163840, p = gid % 163840;
    int y = p / 2560, xx = (p / 40) % 64, z = p % 40;
    float v[13];
#pragma unroll
    for (int i = 0; i < 10; i++) v[i] = xin[(size_t)gid * 10 + i];
    v[10] = (float)((double)y / 63.0);
    v[11] = (float)((double)xx / 63.0);
    v[12] = (float)((double)z / 39.0);
    size_t ob = (size_t)b * 10485760 + p;
    for (int c = 0; c < 64; c++) {
        float a = pb[c];
#pragma unroll
        for (int i = 0; i < 13; i++) a += pw[c * 13 + i] * v[i];
        xo[ob + (size_t)c * 163840] = a;
    }
}

// ---------------- forward z-DFT + x-DFT, b128/b64 LDS reads ----------------
// grid (b,c,y)=8192, 256 threads. phase1: thread owns (xx, xx+32) sharing one
// twiddle stream: 6 LDS insts / 16 FMA per 4-z chunk. phase2: all-b64.
__global__ __launch_bounds__(256) void k_fwd_zx(const float* __restrict__ x,
        const float* __restrict__ tzk, const float* __restrict__ txf,
        float* __restrict__ Fx) {
    int bid = blockIdx.x;
    int b = bid >> 12, c = (bid >> 6) & 63, y = bid & 63;
    int t = threadIdx.x;
    __shared__ __align__(16) float xr_[2560];
    __shared__ __align__(16) float tzs[672];   // [k][42 f2] rows padded to 84 floats
    __shared__ __align__(16) float txs[2944];  // [xx][m][2]
    __shared__ __align__(16) float f1[1024];   // [xx][k][2]
    const float4* xrow4 = (const float4*)(x + ((size_t)((b * 64 + c) * 4096 + y * 64)) * 40);
    for (int idx = t; idx < 640; idx += 256) ((float4*)xr_)[idx] = xrow4[idx];
    for (int idx = t; idx < 160; idx += 256) {
        int k = idx / 20, q = idx % 20;
        ((float4*)tzs)[k * 21 + q] = ((const float4*)tzk)[idx];
    }
    for (int idx = t; idx < 736; idx += 256) ((float4*)txs)[idx] = ((const float4*)txf)[idx];
    __syncthreads();
    {
        int xx = t >> 3, k = t & 7;
        float sr0 = 0.f, si0 = 0.f, sr1 = 0.f, si1 = 0.f;
        const float2* tzp = (const float2*)(tzs + k * 84);
        const float4* X0 = (const float4*)(xr_ + xx * 40);
        const float4* X1 = (const float4*)(xr_ + (xx + 32) * 40);
        for (int zc = 0; zc < 10; zc++) {
            float4 A = X0[zc], B = X1[zc];
            float2 T0 = tzp[zc * 4], T1v = tzp[zc * 4 + 1];
            float2 T2v = tzp[zc * 4 + 2], T3v = tzp[zc * 4 + 3];
            sr0 = fmaf(A.x, T0.x, sr0);  si0 = fmaf(A.x, T0.y, si0);
            sr0 = fmaf(A.y, T1v.x, sr0); si0 = fmaf(A.y, T1v.y, si0);
            sr0 = fmaf(A.z, T2v.x, sr0); si0 = fmaf(A.z, T2v.y, si0);
            sr0 = fmaf(A.w, T3v.x, sr0); si0 = fmaf(A.w, T3v.y, si0);
            sr1 = fmaf(B.x, T0.x, sr1);  si1 = fmaf(B.x, T0.y, si1);
            sr1 = fmaf(B.y, T1v.x, sr1); si1 = fmaf(B.y, T1v.y, si1);
            sr1 = fmaf(B.z, T2v.x, sr1); si1 = fmaf(B.z, T2v.y, si1);
            sr1 = fmaf(B.w, T3v.x, sr1); si1 = fmaf(B.w, T3v.y, si1);
        }
        ((float2*)f1)[xx * 8 + k] = make_float2(sr0, si0);
        ((float2*)f1)[(xx + 32) * 8 + k] = make_float2(sr1, si1);
    }
    __syncthreads();
    if (t < 184) {
        int m = t >> 3, k = t & 7;
        float sr = 0.f, si = 0.f;
        const float2* f1p = (const float2*)f1;
        const float2* txp = (const float2*)txs;
        for (int xx = 0; xx < 64; xx++) {
            float2 a = f1p[xx * 8 + k];
            float2 w = txp[xx * 23 + m];
            sr = fmaf(a.x, w.x, sr); sr = fmaf(-a.y, w.y, sr);
            si = fmaf(a.x, w.y, si); si = fmaf(a.y, w.x, si);
        }
        size_t g = ((size_t)(((b * 64 + c) * 64 + y) * 23 + m) * 8 + k) * 2;
        Fx[g] = sr; Fx[g + 1] = si;
    }
}

// ---------------- forward y-DFT: thread=(n,kpair), b128 s + b64 table --------
__global__ __launch_bounds__(128) void k_fwd_y(const float* __restrict__ Fx,
        const float* __restrict__ txf, float* __restrict__ Xs) {
    int bid = blockIdx.x;
    int b = bid / 1472, rem = bid % 1472, c = rem / 23, m = rem % 23;
    int t = threadIdx.x;
    __shared__ __align__(16) float s[1024];    // [y][k][2]
    __shared__ __align__(16) float txs[2944];
    for (int idx = t; idx < 512; idx += 128) {
        int y = idx >> 3, k = idx & 7;
        size_t g = ((size_t)(((b * 64 + c) * 64 + y) * 23 + m) * 8 + k);
        ((float2*)s)[idx] = ((const float2*)Fx)[g];
    }
    for (int idx = t; idx < 736; idx += 128) ((float4*)txs)[idx] = ((const float4*)txf)[idx];
    __syncthreads();
    if (t < 92) {
        int n = t >> 2, kp = t & 3;
        float sr0 = 0.f, si0 = 0.f, sr1 = 0.f, si1 = 0.f;
        const float2* txp = (const float2*)txs;
        for (int y = 0; y < 64; y++) {
            float4 S = *(const float4*)&s[y * 16 + kp * 4];
            float2 w = txp[y * 23 + n];
            sr0 = fmaf(S.x, w.x, sr0); sr0 = fmaf(-S.y, w.y, sr0);
            si0 = fmaf(S.x, w.y, si0); si0 = fmaf(S.y, w.x, si0);
            sr1 = fmaf(S.z, w.x, sr1); sr1 = fmaf(-S.w, w.y, sr1);
            si1 = fmaf(S.z, w.y, si1); si1 = fmaf(S.w, w.x, si1);
        }
        size_t g = ((size_t)(((b * 64 + c) * 23 + n) * 23 + m)) * 16 + kp * 4;
        *(float4*)&Xs[g] = make_float4(sr0, si0, sr1, si1);
    }
}

// ---------------- mode mixing (unchanged) ----------------
__global__ void k_mix(const float* __restrict__ Xs, const float* __restrict__ WLC,
                      const float* __restrict__ WLR, float* __restrict__ Md) {
    int bid = blockIdx.x;
    int n = bid / 23, m = bid % 23;
    int a = n, c = m, yy, w;
    if (c >= 11) { yy = a; w = c - 11; } else { yy = 22 - a; w = 11 - c; }
    int isLC, idx;
    if (yy >= 12) {
        int p = yy - 12, q = w;
        if (q == 0) { isLC = 1; idx = p + 1; } else { isLC = 0; idx = p * 11 + (q - 1); }
    } else {
        if (w == 0) { isLC = 1; idx = 11 - yy; }
        else {
            int p = w - 1, q = 11 - yy;
            if (q == 0) { isLC = 1; idx = p + 1; } else { isLC = 0; idx = p * 11 + (q - 1); }
        }
    }
    const float* src = isLC ? WLC : WLR;
    int stride = isLC ? 96 : 968;
    int base8 = idx * 8;

    int t = threadIdx.x;
    int o = t >> 3, tt = t & 7;
    __shared__ __align__(16) float wl[8 * 64 * 8];
    __shared__ float xl[256];
    float aR0 = 0.f, aI0 = 0.f, aR1 = 0.f, aI1 = 0.f;
    for (int i0 = 0; i0 < 64; i0 += 8) {
        {
            int il = t >> 6, oo = t & 63;
            const float4* g = (const float4*)(src + (size_t)((i0 + il) * 64 + oo) * stride + base8);
            float4 A = g[0], B = g[1];
            float4* d = (float4*)&wl[(il * 64 + oo) * 8];
            d[0] = A; d[1] = B;
        }
        if (t < 256) {
            int bb = t >> 7, il = (t >> 4) & 7, kk = (t >> 1) & 7, ri = t & 1;
            xl[t] = Xs[((size_t)(((bb * 64 + i0 + il) * 23 + n) * 23 + m) * 8 + kk) * 2 + ri];
        }
        __syncthreads();
#pragma unroll
        for (int il = 0; il < 8; il++) {
            float wv = wl[(il * 64 + o) * 8 + tt];
            float xr0 = xl[(il * 8 + tt) * 2], xi0 = xl[(il * 8 + tt) * 2 + 1];
            float xr1 = xl[128 + (il * 8 + tt) * 2], xi1 = xl[128 + (il * 8 + tt) * 2 + 1];
            aR0 += wv * xr0; aI0 += wv * xi0;
            aR1 += wv * xr1; aI1 += wv * xi1;
        }
        __syncthreads();
    }
    size_t ob0 = ((size_t)((o * 23 + n) * 23 + m) * 8 + tt) * 2;
    size_t ob1 = ((size_t)(((64 + o) * 23 + n) * 23 + m) * 8 + tt) * 2;
    Md[ob0] = aR0; Md[ob0 + 1] = aI0;
    Md[ob1] = aR1; Md[ob1 + 1] = aI1;
}

// ---------------- inverse y: thread=(y,kpair) ----------------
__global__ __launch_bounds__(256) void k_inv_y(const float* __restrict__ Md,
        const float* __restrict__ txi, float* __restrict__ T1) {
    int bid = blockIdx.x;
    int b = bid / 1472, rem = bid % 1472, o = rem / 23, m = rem % 23;
    int t = threadIdx.x;
    __shared__ __align__(16) float s[368];     // [n][k][2]
    __shared__ __align__(16) float txs[2944];
    if (t < 184) {
        int n = t >> 3, kk = t & 7;
        size_t g = ((size_t)(((b * 64 + o) * 23 + n) * 23 + m) * 8 + kk);
        ((float2*)s)[t] = ((const float2*)Md)[g];
    }
    for (int idx = t; idx < 736; idx += 256) ((float4*)txs)[idx] = ((const float4*)txi)[idx];
    __syncthreads();
    int y = t >> 2, kp = t & 3;
    float sr0 = 0.f, si0 = 0.f, sr1 = 0.f, si1 = 0.f;
    const float2* txp = (const float2*)txs;
    for (int n = 0; n < 23; n++) {
        float4 S = *(const float4*)&s[n * 16 + kp * 4];
        float2 w = txp[y * 23 + n];
        sr0 = fmaf(S.x, w.x, sr0); sr0 = fmaf(-S.y, w.y, sr0);
        si0 = fmaf(S.x, w.y, si0); si0 = fmaf(S.y, w.x, si0);
        sr1 = fmaf(S.z, w.x, sr1); sr1 = fmaf(-S.w, w.y, sr1);
        si1 = fmaf(S.z, w.y, si1); si1 = fmaf(S.w, w.x, si1);
    }
    size_t g = ((size_t)(((b * 64 + o) * 64 + y) * 23 + m)) * 16 + kp * 4;
    *(float4*)&T1[g] = make_float4(sr0, si0, sr1, si1);
}

// ---------------- inverse x: thread=(xx,kpair) ----------------
__global__ __launch_bounds__(256) void k_inv_x(const float* __restrict__ T1,
        const float* __restrict__ txi, float* __restrict__ T2) {
    int bid = blockIdx.x;
    int b = bid >> 12, o = (bid >> 6) & 63, y = bid & 63;
    int t = threadIdx.x;
    __shared__ __align__(16) float s[368];     // [m][k][2]
    __shared__ __align__(16) float txs[2944];
    {
        const float4* src = (const float4*)(T1 + (size_t)((b * 64 + o) * 64 + y) * 368);
        if (t < 92) ((float4*)s)[t] = src[t];
    }
    for (int idx = t; idx < 736; idx += 256) ((float4*)txs)[idx] = ((const float4*)txi)[idx];
    __syncthreads();
    int xx = t >> 2, kp = t & 3;
    float sr0 = 0.f, si0 = 0.f, sr1 = 0.f, si1 = 0.f;
    const float2* txp = (const float2*)txs;
    for (int m = 0; m < 23; m++) {
        float4 S = *(const float4*)&s[m * 16 + kp * 4];
        float2 w = txp[xx * 23 + m];
        sr0 = fmaf(S.x, w.x, sr0); sr0 = fmaf(-S.y, w.y, sr0);
        si0 = fmaf(S.x, w.y, si0); si0 = fmaf(S.y, w.x, si0);
        sr1 = fmaf(S.z, w.x, sr1); sr1 = fmaf(-S.w, w.y, sr1);
        si1 = fmaf(S.z, w.y, si1); si1 = fmaf(S.w, w.x, si1);
    }
    size_t g = ((size_t)((b * 64 + o) * 4096 + y * 64 + xx)) * 16 + kp * 4;
    *(float4*)&T2[g] = make_float4(sr0, si0, sr1, si1);
}

// ---------------- inline erf-based GELU (A&S 7.1.26, |err|<=1.5e-7) ----
__device__ __forceinline__ float gelu_fast(float x) {
    float u = x * 0.70710678118654752f;
    float a = fabsf(u);
    float t = 1.0f / (1.0f + 0.3275911f * a);
    float poly = t * (0.254829592f + t * (-0.284496736f + t * (1.421413741f +
                 t * (-1.453152027f + t * 1.061405429f))));
    float erfa = 1.0f - poly * __expf(-a * a);
    float er = copysignf(erfa, u);
    return 0.5f * x * (1.0f + er);
}

// ---------------- mlp1: k-space GEMM + c2r + gelu (unchanged from R8) -------
__global__ __launch_bounds__(256) void k_mlp1(
    const float* __restrict__ t2buf, const float* __restrict__ w1t,
    const float* __restrict__ b1, const float* __restrict__ tz2g,
    float* __restrict__ g) {
    __shared__ __align__(16) float T2s[4096];   // [4 sites][64 i][16]
    __shared__ __align__(16) float w1ls[4096];  // [64 i][64 j]
    __shared__ __align__(16) float Hs[4096];    // [4 sites][64 j][16]
    __shared__ float tzls[640];
    int t = threadIdx.x;
    int site0 = blockIdx.x * 4;
    for (int idx = t; idx < 1024; idx += 256) {
        int sl = idx >> 8, r = idx & 255, i = r >> 2, q = r & 3;
        int site = site0 + sl;
        int b = site >> 12, yx = site & 4095;
        const float4* src = (const float4*)(t2buf + ((size_t)(b * 64 + i) * 4096 + yx) * 16 + q * 4);
        *(float4*)&T2s[sl * 1024 + i * 16 + q * 4] = *src;
    }
    for (int idx = t; idx < 1024; idx += 256)
        *(float4*)&w1ls[idx * 4] = ((const float4*)w1t)[idx];
    for (int idx = t; idx < 640; idx += 256) tzls[idx] = tz2g[idx];
    __syncthreads();
    {
        int sl = t >> 6, u = t & 63;
        int j0 = (u >> 2) * 4, kr0 = (u & 3) * 4;
        float c0 = 0.f, c1 = 0.f, c2 = 0.f, c3 = 0.f, c4 = 0.f, c5 = 0.f, c6 = 0.f, c7 = 0.f;
        float c8 = 0.f, c9 = 0.f, c10 = 0.f, c11 = 0.f, c12 = 0.f, c13 = 0.f, c14 = 0.f, c15 = 0.f;
        int tb = sl * 1024 + kr0;
        for (int i = 0; i < 64; i++) {
            float4 W = *(const float4*)&w1ls[i * 64 + j0];
            float4 T = *(const float4*)&T2s[tb + i * 16];
            c0  = fmaf(W.x, T.x, c0);  c1  = fmaf(W.x, T.y, c1);
            c2  = fmaf(W.x, T.z, c2);  c3  = fmaf(W.x, T.w, c3);
            c4  = fmaf(W.y, T.x, c4);  c5  = fmaf(W.y, T.y, c5);
            c6  = fmaf(W.y, T.z, c6);  c7  = fmaf(W.y, T.w, c7);
            c8  = fmaf(W.z, T.x, c8);  c9  = fmaf(W.z, T.y, c9);
            c10 = fmaf(W.z, T.z, c10); c11 = fmaf(W.z, T.w, c11);
            c12 = fmaf(W.w, T.x, c12); c13 = fmaf(W.w, T.y, c13);
            c14 = fmaf(W.w, T.z, c14); c15 = fmaf(W.w, T.w, c15);
        }
        int hb = sl * 1024 + j0 * 16 + kr0;
        *(float4*)&Hs[hb]      = make_float4(c0, c1, c2, c3);
        *(float4*)&Hs[hb + 16] = make_float4(c4, c5, c6, c7);
        *(float4*)&Hs[hb + 32] = make_float4(c8, c9, c10, c11);
        *(float4*)&Hs[hb + 48] = make_float4(c12, c13, c14, c15);
    }
    __syncthreads();
    {
        int sl = t >> 6, j = t & 63;
        int site = site0 + sl;
        int b = site >> 12, yx = site & 4095;
        int hb = sl * 1024 + j * 16;
        float4 H0 = *(const float4*)&Hs[hb];
        float4 H1 = *(const float4*)&Hs[hb + 4];
        float4 H2 = *(const float4*)&Hs[hb + 8];
        float4 H3 = *(const float4*)&Hs[hb + 12];
        float b1j = b1[j];
        size_t obase = (size_t)j * 327680 + (size_t)b * 163840 + yx * 40;
        for (int zc = 0; zc < 10; zc++) {
            float4 outv;
#pragma unroll
            for (int zi = 0; zi < 4; zi++) {
                int z = zc * 4 + zi;
                const float4* tz = (const float4*)&tzls[z * 16];
                float4 T0 = tz[0], T1v = tz[1], T2v = tz[2], T3 = tz[3];
                float v = H0.x * T0.x;
                v = fmaf(H0.y, T0.y, v); v = fmaf(H0.z, T0.z, v); v = fmaf(H0.w, T0.w, v);
                v = fmaf(H1.x, T1v.x, v); v = fmaf(H1.y, T1v.y, v);
                v = fmaf(H1.z, T1v.z, v); v = fmaf(H1.w, T1v.w, v);
                v = fmaf(H2.x, T2v.x, v); v = fmaf(H2.y, T2v.y, v);
                v = fmaf(H2.z, T2v.z, v); v = fmaf(H2.w, T2v.w, v);
                v = fmaf(H3.x, T3.x, v); v = fmaf(H3.y, T3.y, v);
                v = fmaf(H3.z, T3.z, v); v = fmaf(H3.w, T3.w, v);
                float h = b1j + v;
                float gv = gelu_fast(h);
                if (zi == 0) outv.x = gv; else if (zi == 1) outv.y = gv;
                else if (zi == 2) outv.z = gv; else outv.w = gv;
            }
            *(float4*)&g[obase + zc * 4] = outv;
        }
    }
}

// ---------------- mlp2 v3: 8o x 8p register tile, x/g from GLOBAL -----------
// LDS delivers only weights (2 b128 per 64 FMA-inst). 256 points/block, in-place
// safe: block touches only its own point range; x reads precede stores.
#define FMAR8(R, Wc) \
    a##R##0 = fmaf(Wc, X0.x, a##R##0); a##R##1 = fmaf(Wc, X0.y, a##R##1); \
    a##R##2 = fmaf(Wc, X0.z, a##R##2); a##R##3 = fmaf(Wc, X0.w, a##R##3); \
    a##R##4 = fmaf(Wc, X1.x, a##R##4); a##R##5 = fmaf(Wc, X1.y, a##R##5); \
    a##R##6 = fmaf(Wc, X1.z, a##R##6); a##R##7 = fmaf(Wc, X1.w, a##R##7);

__global__ __launch_bounds__(256) void k_mlp2(
    const float* __restrict__ g, float* __restrict__ x,
    const float* __restrict__ w2t, const float* __restrict__ b2,
    const float* __restrict__ wwt, const float* __restrict__ wb, int dorelu) {
    __shared__ __align__(16) float wls[4096];  // [64][64]
    int t = threadIdx.x;
    int P0 = blockIdx.x * 256;
    int b = P0 / 163840, pl = P0 % 163840;
    size_t xbase = (size_t)b * 10485760 + pl;
    int o0 = (t >> 5) * 8, p0 = (t & 31) * 8;
#define INITR(R) float a##R##0 = b2[o0 + R] + wb[o0 + R]; \
    float a##R##1 = a##R##0, a##R##2 = a##R##0, a##R##3 = a##R##0, \
          a##R##4 = a##R##0, a##R##5 = a##R##0, a##R##6 = a##R##0, a##R##7 = a##R##0;
    INITR(0) INITR(1) INITR(2) INITR(3) INITR(4) INITR(5) INITR(6) INITR(7)
#undef INITR
    for (int idx = t; idx < 1024; idx += 256)
        ((float4*)wls)[idx] = ((const float4*)wwt)[idx];
    __syncthreads();
    for (int i = 0; i < 64; i++) {
        const float4* wp = (const float4*)&wls[i * 64 + o0];
        float4 W0 = wp[0], W1 = wp[1];
        const float* xp = x + xbase + (size_t)i * 163840 + p0;
        float4 X0 = *(const float4*)xp, X1 = *(const float4*)(xp + 4);
        FMAR8(0, W0.x) FMAR8(1, W0.y) FMAR8(2, W0.z) FMAR8(3, W0.w)
        FMAR8(4, W1.x) FMAR8(5, W1.y) FMAR8(6, W1.z) FMAR8(7, W1.w)
    }
    __syncthreads();
    for (int idx = t; idx < 1024; idx += 256)
        ((float4*)wls)[idx] = ((const float4*)w2t)[idx];
    __syncthreads();
    for (int j = 0; j < 64; j++) {
        const float4* wp = (const float4*)&wls[j * 64 + o0];
        float4 W0 = wp[0], W1 = wp[1];
        const float* gp = g + (size_t)j * 327680 + P0 + p0;
        float4 X0 = *(const float4*)gp, X1 = *(const float4*)(gp + 4);
        FMAR8(0, W0.x) FMAR8(1, W0.y) FMAR8(2, W0.z) FMAR8(3, W0.w)
        FMAR8(4, W1.x) FMAR8(5, W1.y) FMAR8(6, W1.z) FMAR8(7, W1.w)
    }
#define STROW(R) { \
        float4 R0, R1; \
        if (dorelu) { \
            R0 = make_float4(fmaxf(a##R##0, 0.f), fmaxf(a##R##1, 0.f), fmaxf(a##R##2, 0.f), fmaxf(a##R##3, 0.f)); \
            R1 = make_float4(fmaxf(a##R##4, 0.f), fmaxf(a##R##5, 0.f), fmaxf(a##R##6, 0.f), fmaxf(a##R##7, 0.f)); \
        } else { \
            R0 = make_float4(a##R##0, a##R##1, a##R##2, a##R##3); \
            R1 = make_float4(a##R##4, a##R##5, a##R##6, a##R##7); \
        } \
        float* op = x + xbase + (size_t)(o0 + R) * 163840 + p0; \
        *(float4*)op = R0; *(float4*)(op + 4) = R1; }
    STROW(0) STROW(1) STROW(2) STROW(3) STROW(4) STROW(5) STROW(6) STROW(7)
#undef STROW
}

// ---------------- final head v12 = R6's v7 verbatim (measured best: 180us) --
// Survey closed (R3-R10): SMEM 4x s_load_dwordx4 @128pt/2-per-lane = 180 (best);
// x16 fusion 184-188 (monolithic lgkmcnt unit beats incremental retirement);
// per-lane LDS 205; LDS-bcast 217; VMEM-bcast 631. Plateau is issue/latency-
// structural (not byte-, TLP-, or DS-bound): R6 vs R7 (2x SMEM traffic, 2x TLP)
// both ~180. Reverting to the exact measured-best variant.
__global__ __launch_bounds__(256) void k_head(
    const float* __restrict__ xcur, const float* __restrict__ q1t,
    const float* __restrict__ qb1, const float* __restrict__ qw2,
    const float* __restrict__ qb2, float* __restrict__ outp) {
    __shared__ __align__(16) float Xl[8192];   // [64 i][128 p]; reused as reduce buf
    int t = threadIdx.x;
    int P0 = blockIdx.x * 128;              // 163840 % 128 == 0: no b straddle
    int b = P0 / 163840, pl = P0 % 163840;
    size_t xbase = (size_t)b * 10485760 + pl;
    for (int idx = t; idx < 2048; idx += 256) {
        int i = idx >> 5, q = idx & 31;
        *(float4*)&Xl[i * 128 + q * 4] =
            *(const float4*)(xcur + xbase + (size_t)i * 163840 + q * 4);
    }
    __syncthreads();
    int w = t >> 6, lane = t & 63;
    int jb = __builtin_amdgcn_readfirstlane(w * 64);  // force SGPR j-base
    float outa0 = 0.f, outa1 = 0.f;
#define FMAJ(JJ, Wc) \
    accA##JJ = fmaf(Wc, x0, accA##JJ); accB##JJ = fmaf(Wc, x1, accB##JJ);
    for (int pass = 0; pass < 4; ++pass) {
        int j0 = jb + pass * 16;
        float accA0 = 0.f, accA1 = 0.f, accA2 = 0.f, accA3 = 0.f;
        float accA4 = 0.f, accA5 = 0.f, accA6 = 0.f, accA7 = 0.f;
        float accA8 = 0.f, accA9 = 0.f, accA10 = 0.f, accA11 = 0.f;
        float accA12 = 0.f, accA13 = 0.f, accA14 = 0.f, accA15 = 0.f;
        float accB0 = 0.f, accB1 = 0.f, accB2 = 0.f, accB3 = 0.f;
        float accB4 = 0.f, accB5 = 0.f, accB6 = 0.f, accB7 = 0.f;
        float accB8 = 0.f, accB9 = 0.f, accB10 = 0.f, accB11 = 0.f;
        float accB12 = 0.f, accB13 = 0.f, accB14 = 0.f, accB15 = 0.f;
        for (int i = 0; i < 64; ++i) {
            float x0 = Xl[i * 128 + lane];
            float x1 = Xl[i * 128 + 64 + lane];
            const float* wp = q1t + i * 256 + j0;   // wave-uniform -> s_load
            float4 W0 = *(const float4*)(wp);
            float4 W1 = *(const float4*)(wp + 4);
            float4 W2 = *(const float4*)(wp + 8);
            float4 W3 = *(const float4*)(wp + 12);
            FMAJ(0, W0.x)  FMAJ(1, W0.y)  FMAJ(2, W0.z)  FMAJ(3, W0.w)
            FMAJ(4, W1.x)  FMAJ(5, W1.y)  FMAJ(6, W1.z)  FMAJ(7, W1.w)
            FMAJ(8, W2.x)  FMAJ(9, W2.y)  FMAJ(10, W2.z) FMAJ(11, W2.w)
            FMAJ(12, W3.x) FMAJ(13, W3.y) FMAJ(14, W3.z) FMAJ(15, W3.w)
        }
#define EPIJ(JJ) { float bj = qb1[j0 + JJ]; float wj = qw2[j0 + JJ]; \
        outa0 = fmaf(wj, gelu_fast(accA##JJ + bj), outa0); \
        outa1 = fmaf(wj, gelu_fast(accB##JJ + bj), outa1); }
        EPIJ(0) EPIJ(1) EPIJ(2) EPIJ(3) EPIJ(4) EPIJ(5) EPIJ(6) EPIJ(7)
        EPIJ(8) EPIJ(9) EPIJ(10) EPIJ(11) EPIJ(12) EPIJ(13) EPIJ(14) EPIJ(15)
#undef EPIJ
    }
#undef FMAJ
    // cross-wave reduce overlaid on Xl (all passes done -> Xl reads finished)
    __syncthreads();
    Xl[w * 132 + lane] = outa0;
    Xl[w * 132 + 64 + lane] = outa1;
    __syncthreads();
    if (t < 128) {
        float s = qb2[0];
#pragma unroll
        for (int w2 = 0; w2 < 4; ++w2) s += Xl[w2 * 132 + t];
        outp[P0 + t] = s;
    }
}

extern "C" void kernel_launch(void* const* d_in, const int* in_sizes, int n_in,
                              void* d_out, int out_size, void* d_ws, size_t ws_size,
                              hipStream_t stream) {
    const float* x_in = (const float*)d_in[0];
    const float* p_w  = (const float*)d_in[1];
    const float* p_b  = (const float*)d_in[2];
    const float* W_LC = (const float*)d_in[3];
    const float* W_LR = (const float*)d_in[4];
    const float* m_w1 = (const float*)d_in[5];
    const float* m_b1 = (const float*)d_in[6];
    const float* m_w2 = (const float*)d_in[7];
    const float* m_b2 = (const float*)d_in[8];
    const float* w_w  = (const float*)d_in[9];
    const float* w_b  = (const float*)d_in[10];
    const float* q_w1 = (const float*)d_in[11];
    const float* q_b1 = (const float*)d_in[12];
    const float* q_w2 = (const float*)d_in[13];
    const float* q_b2 = (const float*)d_in[14];

    char* ws = (char*)d_ws;
    // table region [0, 65536)
    float* tzf = (float*)(ws + 0);        // 2560 B
    float* tzi = (float*)(ws + 2560);     // 2560 B
    float* tz2 = (float*)(ws + 5120);     // 2560 B
    float* tzk = (float*)(ws + 7680);     // 2560 B
    float* txf = (float*)(ws + 10240);    // 11776 B
    float* txi = (float*)(ws + 22016);    // 11776 B -> 33792
    float* w2t = (float*)(ws + 65536);
    float* wwt = (float*)(ws + 131072);
    float* w1t = (float*)(ws + 196608);
    float* q1t = (float*)(ws + 262144);   // 65536 B: qw1 transposed [64][256]
    size_t off = 327680;
    float* xA = (float*)(ws + off); off += 83886080ull;
    float* gbuf = (float*)(ws + off); off += 83886080ull;
    float* Fx = (float*)(ws + off); off += 12058624ull;
    float* Xs = (float*)(ws + off); off += 4333568ull;
    float* Md = (float*)(ws + off); off += 4333568ull;
    float* T1 = (float*)(ws + off); off += 12058624ull;
    float* T2 = (float*)(ws + off); off += 33554432ull;

    k_tables<<<6, 256, 0, stream>>>(tzf, tzi, tz2, tzk, txf, txi);
    k_wtrans<<<64, 256, 0, stream>>>(m_w2, w_w, m_w1, q_w1, w2t, wwt, w1t, q1t);
    k_lift<<<1280, 256, 0, stream>>>(x_in, p_w, p_b, xA);

    for (int l = 0; l < 4; l++) {
        k_fwd_zx<<<8192, 256, 0, stream>>>(xA, tzk, txf, Fx);
        k_fwd_y<<<2944, 128, 0, stream>>>(Fx, txf, Xs);
        k_mix<<<529, 512, 0, stream>>>(Xs, W_LC + (size_t)l * 393216,
                                       W_LR + (size_t)l * 3964928, Md);
        k_inv_y<<<2944, 256, 0, stream>>>(Md, txi, T1);
        k_inv_x<<<8192, 256, 0, stream>>>(T1, txi, T2);
        k_mlp1<<<2048, 256, 0, stream>>>(T2, w1t + (size_t)l * 4096, m_b1 + l * 64,
                                         tz2, gbuf);
        k_mlp2<<<1280, 256, 0, stream>>>(gbuf, xA, w2t + (size_t)l * 4096, m_b2 + l * 64,
                                         wwt + (size_t)l * 4096, w_b + l * 64,
                                         (l < 3) ? 1 : 0);
    }
    k_head<<<2560, 256, 0, stream>>>(xA, q1t, q_b1, q_w2, q_b2, (float*)d_out);
}